// Round 13
// baseline (593.771 us; speedup 1.0000x reference)
//
#include <hip/hip_runtime.h>
#include <hip/hip_bf16.h>
#include <math.h>

#define NNODES 100000
#define NEDGES 1600000
#define EPLUS  (NEDGES + NNODES)   // edges + self loops
#define INF    128
#define HF     64
#define NEG_SLOPE 0.2f

#define CHUNK  4096                 // edges per partition block
#define NCH    416                  // ceil(EPLUS / CHUNK)
#define K1SH   10                   // coarse bucket = dst >> 10 (1024 nodes)
#define NBK    98                   // ceil(NNODES / 1024)
#define HTLEN  (NBK * NCH)          // 40768 (mult of 4)

__device__ __forceinline__ void edge_at(const int* __restrict__ ei, int i, int& s, int& d) {
    if (i < NEDGES) { s = ei[i]; d = ei[NEDGES + i]; } else { s = d = i - NEDGES; }
}

// ---- pass 1: per-chunk histogram over 98 coarse buckets (LDS), write transposed ----
__global__ __launch_bounds__(256) void k_p1hist(const int* __restrict__ ei, int* __restrict__ hT) {
    __shared__ int h[NBK];
    const int c = blockIdx.x, t = threadIdx.x;
    if (t < NBK) h[t] = 0;
    __syncthreads();
    #pragma unroll
    for (int j = 0; j < CHUNK / 256; ++j) {
        int i = c * CHUNK + j * 256 + t;
        if (i < EPLUS) {
            int d = (i < NEDGES) ? ei[NEDGES + i] : (i - NEDGES);
            atomicAdd(&h[d >> K1SH], 1);
        }
    }
    __syncthreads();
    if (t < NBK) hT[t * NCH + c] = h[t];
}

// ---- pass 2: single-block exclusive scan of hT[HTLEN] (int4, wave-scan) ----
__global__ __launch_bounds__(1024) void k_p2scan(int* __restrict__ hT, int* __restrict__ roff) {
    __shared__ int wsum[16], wpre[16];
    __shared__ int carry;
    const int t = threadIdx.x, lane = t & 63, w = t >> 6;
    if (t == 0) carry = 0;
    __syncthreads();
    const int len4 = HTLEN / 4;
    for (int base4 = 0; base4 < len4; base4 += 1024) {
        int idx4 = base4 + t;
        int4 a = make_int4(0, 0, 0, 0);
        if (idx4 < len4) a = ((const int4*)hT)[idx4];
        int s = a.x + a.y + a.z + a.w;
        int inc = s;
        #pragma unroll
        for (int o = 1; o < 64; o <<= 1) { int u = __shfl_up(inc, o); if (lane >= o) inc += u; }
        if (lane == 63) wsum[w] = inc;
        __syncthreads();
        if (t < 16) {
            int v = wsum[t], iv = v;
            #pragma unroll
            for (int o = 1; o < 16; o <<= 1) { int u = __shfl_up(iv, o); if (t >= o) iv += u; }
            wpre[t] = iv - v;
        }
        __syncthreads();
        int cl = carry;
        int excl = inc - s + wpre[w] + cl;
        if (idx4 < len4) {
            int4 e; e.x = excl; e.y = e.x + a.x; e.z = e.y + a.y; e.w = e.z + a.z;
            ((int4*)hT)[idx4] = e;
        }
        __syncthreads();
        if (t == 1023) carry = cl + wpre[15] + wsum[15];
        __syncthreads();
    }
    if (t == 0) roff[NNODES] = EPLUS;
}

// ---- pass 3: partition into bucket-contiguous regions; no global atomics ----
__global__ __launch_bounds__(256) void k_p3part(const int* __restrict__ ei,
        const int* __restrict__ hT, int* __restrict__ pairs) {
    __shared__ int cur[NBK];
    const int c = blockIdx.x, t = threadIdx.x;
    if (t < NBK) cur[t] = hT[t * NCH + c];
    __syncthreads();
    #pragma unroll
    for (int j = 0; j < CHUNK / 256; ++j) {
        int i = c * CHUNK + j * 256 + t;
        if (i < EPLUS) {
            int s, d; edge_at(ei, i, s, d);
            int pos = atomicAdd(&cur[d >> K1SH], 1);
            pairs[pos] = (s << K1SH) | (d & 1023);
        }
    }
}

// ---- pass 4: block per bucket -> per-node counts, roff, ordered csr ----
__global__ __launch_bounds__(512) void k_p4local(const int* __restrict__ hT,
        const int* __restrict__ pairs, int* __restrict__ roff, int* __restrict__ csr) {
    __shared__ int cnt[1024], woffl[1024];
    __shared__ int wsum[8], wpre[8];
    const int k = blockIdx.x, t = threadIdx.x, lane = t & 63, w = t >> 6;
    const int rstart = hT[k * NCH];
    const int rend   = (k + 1 < NBK) ? hT[(k + 1) * NCH] : EPLUS;
    cnt[t] = 0; cnt[t + 512] = 0;
    __syncthreads();
    for (int i = rstart + t; i < rend; i += 512) atomicAdd(&cnt[pairs[i] & 1023], 1);
    __syncthreads();
    int c0 = cnt[2 * t], c1 = cnt[2 * t + 1];
    int s = c0 + c1, inc = s;
    #pragma unroll
    for (int o = 1; o < 64; o <<= 1) { int u = __shfl_up(inc, o); if (lane >= o) inc += u; }
    if (lane == 63) wsum[w] = inc;
    __syncthreads();
    if (t < 8) {
        int v = wsum[t], iv = v;
        #pragma unroll
        for (int o = 1; o < 8; o <<= 1) { int u = __shfl_up(iv, o); if (t >= o) iv += u; }
        wpre[t] = iv - v;
    }
    __syncthreads();
    int excl = inc - s + wpre[w];
    woffl[2 * t] = excl; woffl[2 * t + 1] = excl + c0;
    int gn = (k << 10) + 2 * t;
    if (gn < NNODES)     roff[gn]     = rstart + excl;
    if (gn + 1 < NNODES) roff[gn + 1] = rstart + excl + c0;
    __syncthreads();
    for (int i = rstart + t; i < rend; i += 512) {
        int p = pairs[i];
        int lpos = atomicAdd(&woffl[p & 1023], 1);
        csr[rstart + lpos] = p >> K1SH;
    }
}

// ---- transform: H = X@W, ls = H@asrc, ld = H@adst ----
template<int IN>
__global__ __launch_bounds__(256) void k_transform(const float* __restrict__ X,
        const float* __restrict__ W, const float* __restrict__ asrc, const float* __restrict__ adst,
        float* __restrict__ H, float* __restrict__ ls, float* __restrict__ ld) {
    __shared__ float Wl[IN * HF];       // 32 KB (IN=128) / 16 KB (IN=64)
    __shared__ float Xs[64 * 65];       // 16.6 KB
    __shared__ float lssm[64], ldsm[64];
    const int t = threadIdx.x;
    for (int i = t * 4; i < IN * HF; i += 1024) *(float4*)&Wl[i] = *(const float4*)&W[i];

    const int nb = blockIdx.x * 64;
    const int nl = t & 63;
    const int f0 = (t >> 6) * 16;

    float acc[16] = {0.f,0.f,0.f,0.f,0.f,0.f,0.f,0.f,0.f,0.f,0.f,0.f,0.f,0.f,0.f,0.f};

    for (int kc = 0; kc < IN; kc += 64) {
        __syncthreads();
        #pragma unroll
        for (int it = 0; it < 4; ++it) {
            int i = t + it * 256;
            int r = i >> 4, c = i & 15;
            float4 xv = make_float4(0.f, 0.f, 0.f, 0.f);
            if (nb + r < NNODES) xv = *(const float4*)&X[(long long)(nb + r) * IN + kc + c * 4];
            Xs[r * 65 + c * 4 + 0] = xv.x;
            Xs[r * 65 + c * 4 + 1] = xv.y;
            Xs[r * 65 + c * 4 + 2] = xv.z;
            Xs[r * 65 + c * 4 + 3] = xv.w;
        }
        __syncthreads();
        #pragma unroll 4
        for (int k = 0; k < 64; ++k) {
            float xk = Xs[nl * 65 + k];
            #pragma unroll
            for (int f4 = 0; f4 < 4; ++f4) {
                float4 wv = *(const float4*)&Wl[(kc + k) * HF + f0 + f4 * 4];
                acc[f4 * 4 + 0] += xk * wv.x;
                acc[f4 * 4 + 1] += xk * wv.y;
                acc[f4 * 4 + 2] += xk * wv.z;
                acc[f4 * 4 + 3] += xk * wv.w;
            }
        }
    }

    if (t < 64) { lssm[t] = 0.f; ldsm[t] = 0.f; }
    __syncthreads();
    float hs = 0.f, hd = 0.f;
    #pragma unroll
    for (int f4 = 0; f4 < 4; ++f4) {
        float4 av = *(const float4*)&asrc[f0 + f4 * 4];
        float4 dv = *(const float4*)&adst[f0 + f4 * 4];
        hs += acc[f4*4+0]*av.x + acc[f4*4+1]*av.y + acc[f4*4+2]*av.z + acc[f4*4+3]*av.w;
        hd += acc[f4*4+0]*dv.x + acc[f4*4+1]*dv.y + acc[f4*4+2]*dv.z + acc[f4*4+3]*dv.w;
    }
    atomicAdd(&lssm[nl], hs);
    atomicAdd(&ldsm[nl], hd);
    if (nb + nl < NNODES) {
        #pragma unroll
        for (int f4 = 0; f4 < 4; ++f4)
            *(float4*)&H[(long long)(nb + nl) * HF + f0 + f4 * 4] =
                make_float4(acc[f4*4+0], acc[f4*4+1], acc[f4*4+2], acc[f4*4+3]);
    }
    __syncthreads();
    if (t < 64 && nb + t < NNODES) { ls[nb + t] = lssm[t]; ld[nb + t] = ldsm[t]; }
}

// ---- XCD-sliced CSR aggregation: wave handles ONE dst node x ONE 16-feature
// slice (= one 64B line of each gathered H row). blockIdx (mod 8) pins the
// slice to an XCD pair -> per-XCD H working set 25.6 -> 6.4 MB (L2-resident).
// Lane = edge-slot(16) x feature-lane(4): each load instruction fetches 16
// independent edges' lines. No max-shift (e bounded); no cross-lane ops in
// the loop; divergence granularity is 4-lane (es-uniform), no shfl inside. ----
__global__ __launch_bounds__(256) void k_gat_slice(const int* __restrict__ roff,
        const int* __restrict__ csr, const float* __restrict__ ls, const float* __restrict__ ld,
        const float* __restrict__ H, const float* __restrict__ b, float* __restrict__ outX) {
    const int bid  = blockIdx.x;
    const int wv   = threadIdx.x >> 6;
    const int lane = threadIdx.x & 63;
    const int es   = lane >> 2;                    // edge slot 0..15
    const int fl   = lane & 3;                     // feature quad 0..3
    const int grp  = (bid >> 3) * 2 + (bid & 1);   // node group 0..24999
    const int slice = (bid & 7) >> 1;              // 0..3 (XCD pair 2s,2s+1)
    const int n = grp * 4 + wv;
    if (n >= NNODES) return;
    const int r0 = roff[n], r1 = roff[n + 1];
    const float ldv = ld[n];
    const float* __restrict__ Hs = H + slice * 16 + fl * 4;   // slice line base

    float den = 0.f;
    float4 aA = make_float4(0.f,0.f,0.f,0.f), aB = make_float4(0.f,0.f,0.f,0.f);
    int i = r0 + es;
    for (; i + 16 < r1; i += 32) {
        int   s0 = csr[i];         int   s1 = csr[i + 16];
        float e0 = ls[s0] + ldv;   float e1 = ls[s1] + ldv;
        e0 = e0 > 0.f ? e0 : NEG_SLOPE * e0;
        e1 = e1 > 0.f ? e1 : NEG_SLOPE * e1;
        float p0 = __expf(e0), p1 = __expf(e1);
        den += p0 + p1;
        float4 h0 = *(const float4*)&Hs[(long long)s0 * HF];
        float4 h1 = *(const float4*)&Hs[(long long)s1 * HF];
        aA.x += p0 * h0.x; aA.y += p0 * h0.y; aA.z += p0 * h0.z; aA.w += p0 * h0.w;
        aB.x += p1 * h1.x; aB.y += p1 * h1.y; aB.z += p1 * h1.z; aB.w += p1 * h1.w;
    }
    if (i < r1) {
        int   s0 = csr[i];
        float e0 = ls[s0] + ldv;
        e0 = e0 > 0.f ? e0 : NEG_SLOPE * e0;
        float p0 = __expf(e0);
        den += p0;
        float4 h0 = *(const float4*)&Hs[(long long)s0 * HF];
        aA.x += p0 * h0.x; aA.y += p0 * h0.y; aA.z += p0 * h0.z; aA.w += p0 * h0.w;
    }

    // reduce across the 16 edge slots (lane bits 2..5)
    float4 acc = make_float4(aA.x + aB.x, aA.y + aB.y, aA.z + aB.z, aA.w + aB.w);
    #pragma unroll
    for (int o = 4; o <= 32; o <<= 1) {
        den   += __shfl_xor(den,   o);
        acc.x += __shfl_xor(acc.x, o);
        acc.y += __shfl_xor(acc.y, o);
        acc.z += __shfl_xor(acc.z, o);
        acc.w += __shfl_xor(acc.w, o);
    }
    const float inv = 1.f / (den + 1e-16f);
    if (es == 0) {
        const float4 bv = *(const float4*)&b[slice * 16 + fl * 4];
        float4 v;
        v.x = fmaxf(acc.x * inv + bv.x, 0.f);
        v.y = fmaxf(acc.y * inv + bv.y, 0.f);
        v.z = fmaxf(acc.z * inv + bv.z, 0.f);
        v.w = fmaxf(acc.w * inv + bv.w, 0.f);
        *(float4*)&outX[(long long)n * HF + slice * 16 + fl * 4] = v;
    }
}

// ---- classifier: out = relu-free X @ Wc + bc (X already relu'd) ----
__global__ __launch_bounds__(256) void k_cls(const float* __restrict__ X,
        const float* __restrict__ Wc, const float* __restrict__ bc, float* __restrict__ out) {
    long long n = (long long)blockIdx.x * 4 + (threadIdx.x >> 6);
    if (n >= NNODES) return;
    const int lane = threadIdx.x & 63;
    float v = X[n * HF + lane];
    float r0 = v * Wc[lane * 2 + 0];
    float r1 = v * Wc[lane * 2 + 1];
    #pragma unroll
    for (int o = 32; o; o >>= 1) { r0 += __shfl_xor(r0, o); r1 += __shfl_xor(r1, o); }
    if (lane == 0) { out[n * 2 + 0] = r0 + bc[0]; out[n * 2 + 1] = r1 + bc[1]; }
}

extern "C" void kernel_launch(void* const* d_in, const int* in_sizes, int n_in,
                              void* d_out, int out_size, void* d_ws, size_t ws_size,
                              hipStream_t stream) {
    const float* x      = (const float*)d_in[0];
    const int*   ei     = (const int*)d_in[1];
    const float* W0     = (const float*)d_in[2];
    const float* asrc0  = (const float*)d_in[3];
    const float* adst0  = (const float*)d_in[4];
    const float* b0     = (const float*)d_in[5];
    const float* Ws     = (const float*)d_in[6];
    const float* asrcs  = (const float*)d_in[7];
    const float* adsts  = (const float*)d_in[8];
    const float* bs     = (const float*)d_in[9];
    const float* Wc     = (const float*)d_in[10];
    const float* bc     = (const float*)d_in[11];
    float* out = (float*)d_out;

    // workspace layout (~67 MB); all segment starts 16B-aligned
    float* Hb   = (float*)d_ws;                    // N*64
    float* P    = Hb + (long long)NNODES * HF;     // N*64
    float* ls   = P + (long long)NNODES * HF;      // N
    float* ld   = ls + NNODES;                     // N
    int* roff   = (int*)(ld + NNODES);             // N+4 (pad)
    int* hT     = roff + NNODES + 4;               // HTLEN (int4-scanned)
    int* csr    = hT + HTLEN;                      // EPLUS
    int* pairs  = csr + EPLUS;                     // EPLUS

    const int B = 256;
    const int gT     = (NNODES + 63) / 64;
    const int gSlice = 100000;                     // 12500 groups x 8 xcd-slots
    const int gNode4 = (NNODES + 3) / 4;

    // ---- CSR build: contention-free partition sort (reused by all 3 layers) ----
    k_p1hist<<<NCH, B, 0, stream>>>(ei, hT);
    k_p2scan<<<1, 1024, 0, stream>>>(hT, roff);
    k_p3part<<<NCH, B, 0, stream>>>(ei, hT, pairs);
    k_p4local<<<NBK, 512, 0, stream>>>(hT, pairs, roff, csr);

    // ---- layer 0: x(128) -> Hb(h0) -> P(x1) ----
    k_transform<INF><<<gT, B, 0, stream>>>(x, W0, asrc0, adst0, Hb, ls, ld);
    k_gat_slice<<<gSlice, B, 0, stream>>>(roff, csr, ls, ld, Hb, b0, P);

    // ---- layer 1: P -> P(h1, in-place) -> Hb(x2) ----
    k_transform<HF><<<gT, B, 0, stream>>>(P, Ws + 0 * HF * HF, asrcs + 0 * HF, adsts + 0 * HF, P, ls, ld);
    k_gat_slice<<<gSlice, B, 0, stream>>>(roff, csr, ls, ld, P, bs + 0 * HF, Hb);

    // ---- layer 2: Hb -> Hb(h2, in-place) -> P(x3) -> classifier ----
    k_transform<HF><<<gT, B, 0, stream>>>(Hb, Ws + 1 * HF * HF, asrcs + 1 * HF, adsts + 1 * HF, Hb, ls, ld);
    k_gat_slice<<<gSlice, B, 0, stream>>>(roff, csr, ls, ld, Hb, bs + 1 * HF, P);
    k_cls<<<gNode4, B, 0, stream>>>(P, Wc, bc, out);
}

// Round 14
// 350.284 us; speedup vs baseline: 1.6951x; 1.6951x over previous
//
#include <hip/hip_runtime.h>
#include <hip/hip_bf16.h>
#include <math.h>

#define NNODES 100000
#define NEDGES 1600000
#define EPLUS  (NEDGES + NNODES)   // edges + self loops
#define INF    128
#define HF     64
#define NEG_SLOPE 0.2f

#define CHUNK  8192                 // edges per partition block
#define NCH    208                  // ceil(EPLUS / CHUNK)
#define K1SH   10                   // coarse bucket = dst >> 10 (1024 nodes)
#define NBK    98                   // ceil(NNODES / 1024)
#define HTLEN  (NBK * NCH)          // 20384 (mult of 4)

__device__ __forceinline__ void edge_at(const int* __restrict__ ei, int i, int& s, int& d) {
    if (i < NEDGES) { s = ei[i]; d = ei[NEDGES + i]; } else { s = d = i - NEDGES; }
}

// ---- pass 1: per-chunk histogram over 98 coarse buckets (LDS), write transposed ----
__global__ __launch_bounds__(256) void k_p1hist(const int* __restrict__ ei, int* __restrict__ hT) {
    __shared__ int h[NBK];
    const int c = blockIdx.x, t = threadIdx.x;
    if (t < NBK) h[t] = 0;
    __syncthreads();
    #pragma unroll
    for (int j = 0; j < CHUNK / 256; ++j) {
        int i = c * CHUNK + j * 256 + t;
        if (i < EPLUS) {
            int d = (i < NEDGES) ? ei[NEDGES + i] : (i - NEDGES);
            atomicAdd(&h[d >> K1SH], 1);
        }
    }
    __syncthreads();
    if (t < NBK) hT[t * NCH + c] = h[t];
}

// ---- pass 2: single-block exclusive scan of hT[HTLEN] (int4, wave-scan) ----
__global__ __launch_bounds__(1024) void k_p2scan(int* __restrict__ hT, int* __restrict__ roff) {
    __shared__ int wsum[16], wpre[16];
    __shared__ int carry;
    const int t = threadIdx.x, lane = t & 63, w = t >> 6;
    if (t == 0) carry = 0;
    __syncthreads();
    const int len4 = HTLEN / 4;
    for (int base4 = 0; base4 < len4; base4 += 1024) {
        int idx4 = base4 + t;
        int4 a = make_int4(0, 0, 0, 0);
        if (idx4 < len4) a = ((const int4*)hT)[idx4];
        int s = a.x + a.y + a.z + a.w;
        int inc = s;
        #pragma unroll
        for (int o = 1; o < 64; o <<= 1) { int u = __shfl_up(inc, o); if (lane >= o) inc += u; }
        if (lane == 63) wsum[w] = inc;
        __syncthreads();
        if (t < 16) {
            int v = wsum[t], iv = v;
            #pragma unroll
            for (int o = 1; o < 16; o <<= 1) { int u = __shfl_up(iv, o); if (t >= o) iv += u; }
            wpre[t] = iv - v;
        }
        __syncthreads();
        int cl = carry;
        int excl = inc - s + wpre[w] + cl;
        if (idx4 < len4) {
            int4 e; e.x = excl; e.y = e.x + a.x; e.z = e.y + a.y; e.w = e.z + a.z;
            ((int4*)hT)[idx4] = e;
        }
        __syncthreads();
        if (t == 1023) carry = cl + wpre[15] + wsum[15];
        __syncthreads();
    }
    if (t == 0) roff[NNODES] = EPLUS;
}

// ---- pass 3: partition into bucket-contiguous regions; no global atomics ----
__global__ __launch_bounds__(256) void k_p3part(const int* __restrict__ ei,
        const int* __restrict__ hT, int* __restrict__ pairs) {
    __shared__ int cur[NBK];
    const int c = blockIdx.x, t = threadIdx.x;
    if (t < NBK) cur[t] = hT[t * NCH + c];
    __syncthreads();
    #pragma unroll
    for (int j = 0; j < CHUNK / 256; ++j) {
        int i = c * CHUNK + j * 256 + t;
        if (i < EPLUS) {
            int s, d; edge_at(ei, i, s, d);
            int pos = atomicAdd(&cur[d >> K1SH], 1);
            pairs[pos] = (s << K1SH) | (d & 1023);
        }
    }
}

// ---- pass 4: block per bucket (1024 threads, 1 node/thread scan) ----
__global__ __launch_bounds__(1024) void k_p4local(const int* __restrict__ hT,
        const int* __restrict__ pairs, int* __restrict__ roff, int* __restrict__ csr) {
    __shared__ int cnt[1024], woffl[1024];
    __shared__ int wsum[16], wpre[16];
    const int k = blockIdx.x, t = threadIdx.x, lane = t & 63, w = t >> 6;
    const int rstart = hT[k * NCH];
    const int rend   = (k + 1 < NBK) ? hT[(k + 1) * NCH] : EPLUS;
    cnt[t] = 0;
    __syncthreads();
    for (int i = rstart + t; i < rend; i += 1024) atomicAdd(&cnt[pairs[i] & 1023], 1);
    __syncthreads();
    int v = cnt[t], inc = v;
    #pragma unroll
    for (int o = 1; o < 64; o <<= 1) { int u = __shfl_up(inc, o); if (lane >= o) inc += u; }
    if (lane == 63) wsum[w] = inc;
    __syncthreads();
    if (t < 16) {
        int vv = wsum[t], iv = vv;
        #pragma unroll
        for (int o = 1; o < 16; o <<= 1) { int u = __shfl_up(iv, o); if (t >= o) iv += u; }
        wpre[t] = iv - vv;
    }
    __syncthreads();
    int excl = inc - v + wpre[w];
    woffl[t] = excl;
    int gn = (k << 10) + t;
    if (gn < NNODES) roff[gn] = rstart + excl;
    __syncthreads();
    for (int i = rstart + t; i < rend; i += 1024) {
        int p = pairs[i];
        int lpos = atomicAdd(&woffl[p & 1023], 1);
        csr[rstart + lpos] = p >> K1SH;
    }
}

// ---- transform: H = X@W, ls = H@asrc, ld = H@adst ----
template<int IN>
__global__ __launch_bounds__(256) void k_transform(const float* __restrict__ X,
        const float* __restrict__ W, const float* __restrict__ asrc, const float* __restrict__ adst,
        float* __restrict__ H, float* __restrict__ ls, float* __restrict__ ld) {
    __shared__ float Wl[IN * HF];       // 32 KB (IN=128) / 16 KB (IN=64)
    __shared__ float Xs[64 * 65];       // 16.6 KB
    __shared__ float lssm[64], ldsm[64];
    const int t = threadIdx.x;
    for (int i = t * 4; i < IN * HF; i += 1024) *(float4*)&Wl[i] = *(const float4*)&W[i];

    const int nb = blockIdx.x * 64;
    const int nl = t & 63;
    const int f0 = (t >> 6) * 16;

    float acc[16] = {0.f,0.f,0.f,0.f,0.f,0.f,0.f,0.f,0.f,0.f,0.f,0.f,0.f,0.f,0.f,0.f};

    for (int kc = 0; kc < IN; kc += 64) {
        __syncthreads();
        #pragma unroll
        for (int it = 0; it < 4; ++it) {
            int i = t + it * 256;
            int r = i >> 4, c = i & 15;
            float4 xv = make_float4(0.f, 0.f, 0.f, 0.f);
            if (nb + r < NNODES) xv = *(const float4*)&X[(long long)(nb + r) * IN + kc + c * 4];
            Xs[r * 65 + c * 4 + 0] = xv.x;
            Xs[r * 65 + c * 4 + 1] = xv.y;
            Xs[r * 65 + c * 4 + 2] = xv.z;
            Xs[r * 65 + c * 4 + 3] = xv.w;
        }
        __syncthreads();
        #pragma unroll 4
        for (int k = 0; k < 64; ++k) {
            float xk = Xs[nl * 65 + k];
            #pragma unroll
            for (int f4 = 0; f4 < 4; ++f4) {
                float4 wv = *(const float4*)&Wl[(kc + k) * HF + f0 + f4 * 4];
                acc[f4 * 4 + 0] += xk * wv.x;
                acc[f4 * 4 + 1] += xk * wv.y;
                acc[f4 * 4 + 2] += xk * wv.z;
                acc[f4 * 4 + 3] += xk * wv.w;
            }
        }
    }

    if (t < 64) { lssm[t] = 0.f; ldsm[t] = 0.f; }
    __syncthreads();
    float hs = 0.f, hd = 0.f;
    #pragma unroll
    for (int f4 = 0; f4 < 4; ++f4) {
        float4 av = *(const float4*)&asrc[f0 + f4 * 4];
        float4 dv = *(const float4*)&adst[f0 + f4 * 4];
        hs += acc[f4*4+0]*av.x + acc[f4*4+1]*av.y + acc[f4*4+2]*av.z + acc[f4*4+3]*av.w;
        hd += acc[f4*4+0]*dv.x + acc[f4*4+1]*dv.y + acc[f4*4+2]*dv.z + acc[f4*4+3]*dv.w;
    }
    atomicAdd(&lssm[nl], hs);
    atomicAdd(&ldsm[nl], hd);
    if (nb + nl < NNODES) {
        #pragma unroll
        for (int f4 = 0; f4 < 4; ++f4)
            *(float4*)&H[(long long)(nb + nl) * HF + f0 + f4 * 4] =
                make_float4(acc[f4*4+0], acc[f4*4+1], acc[f4*4+2], acc[f4*4+3]);
    }
    __syncthreads();
    if (t < 64 && nb + t < NNODES) { ls[nb + t] = lssm[t]; ld[nb + t] = ldsm[t]; }
}

// ---- CSR aggregation (R9-proven floor): wave per dst node; no max-shift;
// gather 4 edge-slots x 16 lanes x float4, 2-deep; shfls in uniform control
// flow only (bpermute from masked-off source lane is undefined on CDNA). ----
template<int FUSE_CLS>
__global__ __launch_bounds__(256) void k_gat(const int* __restrict__ roff, const int* __restrict__ csr,
        const float* __restrict__ ls, const float* __restrict__ ld, const float* __restrict__ H,
        const float* __restrict__ b, float* __restrict__ outX,
        const float* __restrict__ Wc, const float* __restrict__ bc, float* __restrict__ outC) {
    int n = blockIdx.x * 4 + (threadIdx.x >> 6);
    if (n >= NNODES) return;
    const int lane = threadIdx.x & 63;
    const int es = lane >> 4;        // edge slot 0..3
    const int fg = lane & 15;        // 4-feature group
    const int r0 = roff[n], r1 = roff[n + 1];
    const float ldv = ld[n];
    const float* __restrict__ Hf = H + fg * 4;   // per-lane column base
    float den = 0.f;
    float4 aA = make_float4(0.f,0.f,0.f,0.f), aB = make_float4(0.f,0.f,0.f,0.f);
    for (int base = r0; base < r1; base += 64) {
        const int nb = min(64, r1 - base);
        const bool ok = (lane < nb);
        int  sv = ok ? csr[base + lane] : 0;
        float e = ok ? (ls[sv] + ldv) : -INFINITY;
        e = e > 0.f ? e : NEG_SLOPE * e;          // -inf stays -inf
        float p  = __expf(e);                     // padding lanes -> 0
        float ts = p;
        #pragma unroll
        for (int o = 32; o; o >>= 1) ts += __shfl_xor(ts, o);
        den += ts;
        const int jmax = (nb + 3) >> 2;           // 4-edge groups in this tile
        int j = 0;
        for (; j + 1 < jmax; j += 2) {
            int   j0 = j * 4 + es,      j1 = j0 + 4;
            int   s0 = __shfl(sv, j0),  s1 = __shfl(sv, j1);
            float p0 = __shfl(p,  j0),  p1 = __shfl(p,  j1);
            float4 h0 = *(const float4*)&Hf[(long long)s0 * HF];
            float4 h1 = *(const float4*)&Hf[(long long)s1 * HF];
            aA.x += p0 * h0.x; aA.y += p0 * h0.y; aA.z += p0 * h0.z; aA.w += p0 * h0.w;
            aB.x += p1 * h1.x; aB.y += p1 * h1.y; aB.z += p1 * h1.z; aB.w += p1 * h1.w;
        }
        if (j < jmax) {
            int   j0 = j * 4 + es;
            float p0 = __shfl(p,  j0);            // uniform control flow here
            int   s0 = __shfl(sv, j0);            // hoisted: all lanes active
            if (p0 != 0.f) {                      // skip all-padding groups' loads
                float4 h0 = *(const float4*)&Hf[(long long)s0 * HF];
                aA.x += p0 * h0.x; aA.y += p0 * h0.y; aA.z += p0 * h0.z; aA.w += p0 * h0.w;
            }
        }
    }
    float4 acc = make_float4(aA.x + aB.x, aA.y + aB.y, aA.z + aB.z, aA.w + aB.w);
    #pragma unroll
    for (int o = 16; o <= 32; o <<= 1) {
        acc.x += __shfl_xor(acc.x, o);
        acc.y += __shfl_xor(acc.y, o);
        acc.z += __shfl_xor(acc.z, o);
        acc.w += __shfl_xor(acc.w, o);
    }
    const float inv = 1.f / (den + 1e-16f);
    const float4 bv = *(const float4*)&b[fg * 4];
    float4 v;
    v.x = fmaxf(acc.x * inv + bv.x, 0.f);
    v.y = fmaxf(acc.y * inv + bv.y, 0.f);
    v.z = fmaxf(acc.z * inv + bv.z, 0.f);
    v.w = fmaxf(acc.w * inv + bv.w, 0.f);
    if (!FUSE_CLS) {
        if (es == 0) *(float4*)&outX[(long long)n * HF + fg * 4] = v;
    } else {
        float a0 = 0.f, a1 = 0.f;
        if (es == 0) {
            a0 = v.x * Wc[(fg*4+0)*2+0] + v.y * Wc[(fg*4+1)*2+0] + v.z * Wc[(fg*4+2)*2+0] + v.w * Wc[(fg*4+3)*2+0];
            a1 = v.x * Wc[(fg*4+0)*2+1] + v.y * Wc[(fg*4+1)*2+1] + v.z * Wc[(fg*4+2)*2+1] + v.w * Wc[(fg*4+3)*2+1];
        }
        #pragma unroll
        for (int o = 32; o; o >>= 1) { a0 += __shfl_xor(a0, o); a1 += __shfl_xor(a1, o); }
        if (lane == 0) { outC[n * 2 + 0] = a0 + bc[0]; outC[n * 2 + 1] = a1 + bc[1]; }
    }
}

extern "C" void kernel_launch(void* const* d_in, const int* in_sizes, int n_in,
                              void* d_out, int out_size, void* d_ws, size_t ws_size,
                              hipStream_t stream) {
    const float* x      = (const float*)d_in[0];
    const int*   ei     = (const int*)d_in[1];
    const float* W0     = (const float*)d_in[2];
    const float* asrc0  = (const float*)d_in[3];
    const float* adst0  = (const float*)d_in[4];
    const float* b0     = (const float*)d_in[5];
    const float* Ws     = (const float*)d_in[6];
    const float* asrcs  = (const float*)d_in[7];
    const float* adsts  = (const float*)d_in[8];
    const float* bs     = (const float*)d_in[9];
    const float* Wc     = (const float*)d_in[10];
    const float* bc     = (const float*)d_in[11];
    float* out = (float*)d_out;

    // workspace layout (~67 MB); all segment starts 16B-aligned
    float* Hb   = (float*)d_ws;                    // N*64
    float* P    = Hb + (long long)NNODES * HF;     // N*64
    float* ls   = P + (long long)NNODES * HF;      // N
    float* ld   = ls + NNODES;                     // N
    int* roff   = (int*)(ld + NNODES);             // N+4 (pad)
    int* hT     = roff + NNODES + 4;               // HTLEN (int4-scanned)
    int* csr    = hT + HTLEN;                      // EPLUS
    int* pairs  = csr + EPLUS;                     // EPLUS

    const int B = 256;
    const int gNode4 = (NNODES + 3) / 4;
    const int gT     = (NNODES + 63) / 64;

    // ---- CSR build: contention-free partition sort (reused by all 3 layers) ----
    k_p1hist<<<NCH, B, 0, stream>>>(ei, hT);
    k_p2scan<<<1, 1024, 0, stream>>>(hT, roff);
    k_p3part<<<NCH, B, 0, stream>>>(ei, hT, pairs);
    k_p4local<<<NBK, 1024, 0, stream>>>(hT, pairs, roff, csr);

    // ---- layer 0: x(128) -> Hb(h) -> P(x1) ----
    k_transform<INF><<<gT, B, 0, stream>>>(x, W0, asrc0, adst0, Hb, ls, ld);
    k_gat<0><<<gNode4, B, 0, stream>>>(roff, csr, ls, ld, Hb, b0, P, nullptr, nullptr, nullptr);

    // ---- layer 1: P -> P(h, in-place) -> Hb(x2) ----
    k_transform<HF><<<gT, B, 0, stream>>>(P, Ws + 0 * HF * HF, asrcs + 0 * HF, adsts + 0 * HF, P, ls, ld);
    k_gat<0><<<gNode4, B, 0, stream>>>(roff, csr, ls, ld, P, bs + 0 * HF, Hb, nullptr, nullptr, nullptr);

    // ---- layer 2: Hb -> Hb(h, in-place) -> fused classifier -> out ----
    k_transform<HF><<<gT, B, 0, stream>>>(Hb, Ws + 1 * HF * HF, asrcs + 1 * HF, adsts + 1 * HF, Hb, ls, ld);
    k_gat<1><<<gNode4, B, 0, stream>>>(roff, csr, ls, ld, Hb, bs + 1 * HF, nullptr, Wc, bc, out);
}